// Round 16
// baseline (192.709 us; speedup 1.0000x reference)
//
#include <hip/hip_runtime.h>

// GCN 2-layer fused pipeline for MI355X — round 16.
// Post-mortem r15: build insensitive to bucket sizing (116 us fixed);
// k_fused's LDS-broadcast S-phase serializes ~53 us on the 1-per-CU LDS
// pipe (shared by ~15 waves) while VALU (4 pipes/CU) idles at 84%.
// Change: S-phase back to pure-register readlane (r9, 0 LDS) but KEEPING
// r12's cross-round prefetch (cur/pr register double-buffer, pbuf deleted).
// z-phase keeps LDS sW2 (LDS pipe now free during S-phase). Build: ebuf
// packed to 32 bits ((dst&255)<<24 | src) — halves ebuf traffic.

#define NPB   256        // nodes per bucket (dst >> 8)
#define BKSH  8
#define BMASK 255
#define BE    4096       // edges per k_bin block (16 per thread)
#define CAP   5120       // edge cap per bucket (mean 4092, sigma ~64)
#define NBMAX 512

__device__ __forceinline__ float rdlane(float v, int l) {
    return __int_as_float(__builtin_amdgcn_readlane(__float_as_int(v), l));
}

__global__ void k_zero(int* __restrict__ p, int n) {
    int i = blockIdx.x * blockDim.x + threadIdx.x;
    if (i < n) p[i] = 0;
}

// Bin edges by dst-bucket (dst>>8) into fixed-cap regions [b*CAP, b*CAP+cnt).
// ebuf entry: (dst&255)<<24 | src   (src<2^17, lossless).
__launch_bounds__(256)
__global__ void k_bin(const int* __restrict__ src, const int* __restrict__ dst,
                      int* __restrict__ gcur, unsigned int* __restrict__ ebuf,
                      int E, int nbkt) {
    __shared__ int2 es[BE];
    __shared__ int hist[NBMAX], gpos[NBMAX], lcur[NBMAX];
    int tid = threadIdx.x;
    int eb = blockIdx.x * BE;
    int m = min(BE, E - eb);
    for (int it = 0; it < 4; ++it) {
        int s0 = it * 1024 + tid * 4;
        int e0 = eb + s0;
        if (e0 + 3 < E) {
            int4 s = *reinterpret_cast<const int4*>(src + e0);
            int4 d = *reinterpret_cast<const int4*>(dst + e0);
            es[s0 + 0] = make_int2(s.x, d.x);
            es[s0 + 1] = make_int2(s.y, d.y);
            es[s0 + 2] = make_int2(s.z, d.z);
            es[s0 + 3] = make_int2(s.w, d.w);
        } else {
            for (int k = 0; k < 4; ++k)
                if (e0 + k < E) es[s0 + k] = make_int2(src[e0 + k], dst[e0 + k]);
        }
    }
    for (int b = tid; b < NBMAX; b += 256) { hist[b] = 0; lcur[b] = 0; }
    __syncthreads();
    int j0 = tid * 16, j1 = min(j0 + 16, m);
    for (int j = j0; j < j1; ++j) atomicAdd(&hist[es[j].y >> BKSH], 1);
    __syncthreads();
    for (int b = tid; b < nbkt; b += 256) {
        if (hist[b] > 0) {
            int old = atomicAdd(&gcur[b], hist[b]);
            gpos[b] = b * CAP + old;
            hist[b] = min(hist[b], max(CAP - old, 0));  // overflow clamp
        }
    }
    __syncthreads();
    for (int j = j0; j < j1; ++j) {
        int2 e = es[j];
        int b = e.y >> BKSH;
        int r = atomicAdd(&lcur[b], 1);
        if (r < hist[b])
            ebuf[gpos[b] + r] = ((unsigned)(e.y & BMASK) << 24) | (unsigned)e.x;
    }
}

// Per-bucket CSR build: one 512-thread block per 256-node bucket.
__launch_bounds__(512)
__global__ void k_csr(const unsigned int* __restrict__ ebuf, const int* __restrict__ gcur,
                      const float* __restrict__ x,
                      int* __restrict__ deg, int* __restrict__ offs,
                      float* __restrict__ dinv, float* __restrict__ xd,
                      int* __restrict__ csr, int n) {
    __shared__ int ldeg[NPB], tmp[NPB], lcur[NPB];
    int tid = threadIdx.x;
    int b = blockIdx.x;
    int base = b * CAP;
    int cnt = min(gcur[b], CAP);
    int node0 = b << BKSH;
    if (tid < NPB) ldeg[tid] = 0;
    __syncthreads();
    for (int e = base + tid; e < base + cnt; e += 512)
        atomicAdd(&ldeg[ebuf[e] >> 24], 1);
    __syncthreads();
    if (tid < NPB) tmp[tid] = ldeg[tid];
    __syncthreads();
    for (int off = 1; off < NPB; off <<= 1) {
        int t = (tid < NPB && tid >= off) ? tmp[tid - off] : 0;
        __syncthreads();
        if (tid < NPB) tmp[tid] += t;
        __syncthreads();
    }
    if (tid < NPB) {
        int loff = tmp[tid] - ldeg[tid];  // exclusive
        lcur[tid] = loff;
        int i = node0 + tid;
        if (i < n) {
            int dg = ldeg[tid];
            deg[i] = dg;
            offs[i] = base + loff;
            float di = rsqrtf((float)dg + 1.0f);  // +1: self loop
            dinv[i] = di;
            xd[i] = x[i] * di;
        }
    }
    __syncthreads();
    for (int e = base + tid; e < base + cnt; e += 512) {
        unsigned p = ebuf[e];
        int r = atomicAdd(&lcur[p >> 24], 1);
        csr[base + r] = (int)(p & 0xFFFFFFu);
    }
}

// Layer-1 aggregation, edge-parallel per bucket with LDS float atomics:
// agd[i] = ( dinv[i]*(xd[i] + sum_j xd[j]) , dinv[i] )
__launch_bounds__(512)
__global__ void k_agg1e(const unsigned int* __restrict__ ebuf, const int* __restrict__ gcur,
                        const float* __restrict__ xd, const float* __restrict__ dinv,
                        float2* __restrict__ agd, int n) {
    __shared__ float acc[NPB];
    int tid = threadIdx.x;
    int b = blockIdx.x;
    int base = b * CAP, cnt = min(gcur[b], CAP);
    if (tid < NPB) acc[tid] = 0.0f;
    __syncthreads();
    for (int e = base + tid; e < base + cnt; e += 512) {
        unsigned p = ebuf[e];
        atomicAdd(&acc[p >> 24], xd[p & 0xFFFFFFu]);   // ds_add_f32
    }
    __syncthreads();
    int i = (b << BKSH) + tid;
    if (tid < NPB && i < n) {
        float di = dinv[i];
        agd[i] = make_float2((acc[tid] + xd[i]) * di, di);
    }
}

// Fused layer-2: S[i][f] = sum_{j in N(i)+self} d_j*relu(a_j*W1[f]+b1[f]),
// out[i] = bh + sum_f Wh[f]*relu(dinv_i*(sum_k S[k]*W2[k][f]) + b2[f]).
// 4 nodes/wave; S-phase pure-register readlane (no LDS) + cross-round
// register prefetch; z-phase from LDS sW2 (LDS pipe idle during S-phase).
__launch_bounds__(256)
__global__ void k_fused(const float2* __restrict__ agd,
                        const float* __restrict__ W1, const float* __restrict__ b1,
                        const float* __restrict__ W2, const float* __restrict__ b2,
                        const float* __restrict__ Wh, const float* __restrict__ bh,
                        const int* __restrict__ offs, const int* __restrict__ deg,
                        const int* __restrict__ csr, float* __restrict__ out, int n) {
    __shared__ float sW2[64 * 64];
    for (int i = threadIdx.x; i < 1024; i += 256)
        reinterpret_cast<float4*>(sW2)[i] = reinterpret_cast<const float4*>(W2)[i];
    int wave = threadIdx.x >> 6, lane = threadIdx.x & 63;
    float w1l = W1[lane], b1l = b1[lane];
    float b2l = b2[lane], whl = Wh[lane];
    __syncthreads();

    int base4 = (blockIdx.x * 4 + wave) * 4;    // 4 nodes per wave
    int r = lane >> 4, slot = lane & 15;
    int node = base4 + r;
    bool nv = node < n;
    int dg = nv ? deg[node] : -1;               // -1: no slots valid
    int off = nv ? offs[node] : 0;
    float2 self = nv ? agd[node] : make_float2(0.f, 0.f);

    // wave-uniform round count: max(deg)+1 slots (self appended at slot==deg)
    int m = dg + 1;
    m = max(m, __shfl_xor(m, 16, 64));
    m = max(m, __shfl_xor(m, 32, 64));
    int rounds = (m + 15) >> 4;

    float S0 = 0.f, S1 = 0.f, S2 = 0.f, S3 = 0.f;
    // prefetch round 0's pair
    float2 pr = make_float2(0.f, 0.f);
    if (slot < dg)       pr = agd[csr[off + slot]];
    else if (slot == dg) pr = self;
    for (int t = 0; t < rounds; ++t) {
        float2 cur = pr;                        // current round in registers
        // prefetch round t+1 (hides csr->agd dependent latency under k-loop)
        pr = make_float2(0.f, 0.f);
        if (t + 1 < rounds) {
            int nr = slot + (t + 1) * 16;
            if (nr < dg)       pr = agd[csr[off + nr]];
            else if (nr == dg) pr = self;
        }
#pragma unroll
        for (int k = 0; k < 16; ++k) {
            float a0 = rdlane(cur.x, k),      d0 = rdlane(cur.y, k);
            float a1 = rdlane(cur.x, 16 + k), d1 = rdlane(cur.y, 16 + k);
            float a2 = rdlane(cur.x, 32 + k), d2 = rdlane(cur.y, 32 + k);
            float a3 = rdlane(cur.x, 48 + k), d3 = rdlane(cur.y, 48 + k);
            S0 = fmaf(fmaxf(fmaf(a0, w1l, b1l), 0.f), d0, S0);
            S1 = fmaf(fmaxf(fmaf(a1, w1l, b1l), 0.f), d1, S1);
            S2 = fmaf(fmaxf(fmaf(a2, w1l, b1l), 0.f), d2, S2);
            S3 = fmaf(fmaxf(fmaf(a3, w1l, b1l), 0.f), d3, S3);
        }
    }

    // z[f] = sum_k S[k] * W2[k][f]   (readlane broadcast of S, LDS W2)
    float z0 = 0.f, z1 = 0.f, z2 = 0.f, z3 = 0.f;
#pragma unroll
    for (int k = 0; k < 64; ++k) {
        float wv = sW2[k * 64 + lane];
        z0 = fmaf(rdlane(S0, k), wv, z0);
        z1 = fmaf(rdlane(S1, k), wv, z1);
        z2 = fmaf(rdlane(S2, k), wv, z2);
        z3 = fmaf(rdlane(S3, k), wv, z3);
    }

    // epilogue: v_r = relu(dinv_r * z_r + b2) * Wh, reduce over lanes
    float2 p0 = (base4 + 0 < n) ? agd[base4 + 0] : make_float2(0.f, 0.f);
    float2 p1 = (base4 + 1 < n) ? agd[base4 + 1] : make_float2(0.f, 0.f);
    float2 p2 = (base4 + 2 < n) ? agd[base4 + 2] : make_float2(0.f, 0.f);
    float2 p3 = (base4 + 3 < n) ? agd[base4 + 3] : make_float2(0.f, 0.f);
    float v0 = fmaxf(fmaf(z0, p0.y, b2l), 0.f) * whl;
    float v1 = fmaxf(fmaf(z1, p1.y, b2l), 0.f) * whl;
    float v2 = fmaxf(fmaf(z2, p2.y, b2l), 0.f) * whl;
    float v3 = fmaxf(fmaf(z3, p3.y, b2l), 0.f) * whl;
    for (int o = 32; o; o >>= 1) {
        v0 += __shfl_down(v0, o, 64);
        v1 += __shfl_down(v1, o, 64);
        v2 += __shfl_down(v2, o, 64);
        v3 += __shfl_down(v3, o, 64);
    }
    if (lane == 0) {
        float bhv = bh[0];
        if (base4 + 0 < n) out[base4 + 0] = v0 + bhv;
        if (base4 + 1 < n) out[base4 + 1] = v1 + bhv;
        if (base4 + 2 < n) out[base4 + 2] = v2 + bhv;
        if (base4 + 3 < n) out[base4 + 3] = v3 + bhv;
    }
}

static inline size_t align_up(size_t x, size_t a) { return (x + a - 1) & ~(a - 1); }

extern "C" void kernel_launch(void* const* d_in, const int* in_sizes, int n_in,
                              void* d_out, int out_size, void* d_ws, size_t ws_size,
                              hipStream_t stream) {
    const float* x  = (const float*)d_in[0];
    const int*   ei = (const int*)d_in[1];   // [2, E]
    const float* W1 = (const float*)d_in[2];
    const float* b1 = (const float*)d_in[3];
    const float* W2 = (const float*)d_in[4];
    const float* b2 = (const float*)d_in[5];
    const float* Wh = (const float*)d_in[6];
    const float* bh = (const float*)d_in[7];
    float* out = (float*)d_out;

    int n = in_sizes[0];        // 100000
    int E = in_sizes[1] / 2;    // 1600000
    const int* srcp = ei;
    const int* dstp = ei + E;
    int nbkt = (n + NPB - 1) >> BKSH;   // 391 buckets

    // workspace carve
    char* w = (char*)d_ws;
    size_t ni = align_up((size_t)n * sizeof(int), 256);
    size_t nf = align_up((size_t)n * sizeof(float), 256);
    size_t cb = (size_t)nbkt * CAP;
    int*    gcur = (int*)w;    w += align_up(NBMAX * sizeof(int), 256);
    int*    deg  = (int*)w;    w += ni;
    int*    offs = (int*)w;    w += ni;
    float*  dinv = (float*)w;  w += nf;
    float*  xd   = (float*)w;  w += nf;
    float2* agd  = (float2*)w; w += align_up((size_t)n * sizeof(float2), 256);
    int*    csr  = (int*)w;    w += align_up((cb + 64) * sizeof(int), 256);
    unsigned int* ebuf = (unsigned int*)w; w += align_up(cb * sizeof(unsigned int), 256);

    int nbBin = (E + BE - 1) / BE;   // 391
    int nb16  = (n + 15) / 16;       // 6250

    k_zero<<<2, 256, 0, stream>>>(gcur, NBMAX);
    k_bin<<<nbBin, 256, 0, stream>>>(srcp, dstp, gcur, ebuf, E, nbkt);
    k_csr<<<nbkt, 512, 0, stream>>>(ebuf, gcur, x, deg, offs, dinv, xd, csr, n);
    k_agg1e<<<nbkt, 512, 0, stream>>>(ebuf, gcur, xd, dinv, agd, n);
    k_fused<<<nb16, 256, 0, stream>>>(agd, W1, b1, W2, b2, Wh, bh, offs, deg, csr, out, n);
}